// Round 9
// baseline (139.441 us; speedup 1.0000x reference)
//
#include <hip/hip_runtime.h>
#include <hip/hip_bf16.h>
#include <cstdint>

// TT-linear: y[4096,4096] = x[4096,1024] @ W[1024,4096] + bias
// Kernel 1 (prep): fused x->bf16 convert + W^T reconstruction from TT cores (unchanged).
// Kernel 2 (tt_gemm): Round-9 = R8 (256x256, BK=64, 8 waves 2Mx4N, 32x32x16 MFMA,
//   ks1-read hoisting, 2 barriers/K-tile, counted vmcnt(4)) with the swizzle
//   function FIXED: f(r) = (r&2) | ((r>>2)&1)  (was (r>>1)&3).
//   R8's f violated the conflict-free condition f(r)^f(r+2) & 2 != 0: LDS
//   services b128 as 8-lane batches pairing equal-l31 quads across the two
//   32-lane halves; with row-bit1 absent from chunk-bit1 the batch double-hits
//   4 bank quads -> 2-way conflict (measured 3.1M cyc, ~4/read, = R4's count).
//   New f puts row-bit1 into chunk-bit1: verified all-distinct bank quads for
//   both batch structures, kk=0/1, A and B. (R4<->R5 A/B priced this conflict
//   at +4.5us.)

typedef __bf16 bf16x8 __attribute__((ext_vector_type(8)));
typedef float f32x4 __attribute__((ext_vector_type(4)));
typedef float f32x16 __attribute__((ext_vector_type(16)));

__device__ __forceinline__ void g2lds16(const void* g, void* l) {
    __builtin_amdgcn_global_load_lds(
        (const __attribute__((address_space(1))) void*)g,
        (__attribute__((address_space(3))) void*)l,
        16, 0, 0);
}

// --------------------------------------------------------------------- prep
__global__ __launch_bounds__(256) void prep(
    const float* __restrict__ x, __bf16* __restrict__ xb,
    const float* __restrict__ c0, const float* __restrict__ c1,
    const float* __restrict__ c2, const float* __restrict__ c3,
    __bf16* __restrict__ wt) {
    const int b = blockIdx.x;
    const int t = threadIdx.x;
    if (b < 2048) {
        const int i = (b * 256 + t) * 8;
        float4 a0 = *(const float4*)(x + i);
        float4 a1 = *(const float4*)(x + i + 4);
        bf16x8 o;
        o[0] = (__bf16)a0.x; o[1] = (__bf16)a0.y; o[2] = (__bf16)a0.z; o[3] = (__bf16)a0.w;
        o[4] = (__bf16)a1.x; o[5] = (__bf16)a1.y; o[6] = (__bf16)a1.z; o[7] = (__bf16)a1.w;
        *(bf16x8*)(xb + i) = o;
        return;
    }
    __shared__ float t12[4][16];     // [wave][r2]
    __shared__ float t123[4][512];   // [wave][m3*8+n3][r3]
    __shared__ float c3s[512];       // [(r3*4+m4)*8+n4]
    #pragma unroll
    for (int i = t; i < 512; i += 256) c3s[i] = c3[i];
    const int s = t >> 6;
    const int lane = t & 63;
    const int g = (b - 2048) * 4 + s;
    const int m1 = g >> 9, n1 = (g >> 6) & 7, m2 = (g >> 3) & 7, n2 = g & 7;
    __syncthreads();
    if (lane < 16) {
        const int r2 = lane;
        float sum = 0.f;
        #pragma unroll
        for (int r1 = 0; r1 < 16; ++r1)
            sum += c0[(m1 * 8 + n1) * 16 + r1] * c1[((r1 * 8 + m2) * 8 + n2) * 16 + r2];
        t12[s][r2] = sum;
    }
    __syncthreads();
    #pragma unroll
    for (int idx = lane; idx < 512; idx += 64) {
        const int m3 = idx >> 7, n3 = (idx >> 4) & 7, r3 = idx & 15;
        float sum = 0.f;
        #pragma unroll
        for (int r2 = 0; r2 < 16; ++r2)
            sum += t12[s][r2] * c2[((r2 * 4 + m3) * 8 + n3) * 16 + r3];
        t123[s][(m3 * 8 + n3) * 16 + r3] = sum;
    }
    __syncthreads();
    const int n3 = lane >> 3, n4 = lane & 7;
    const int n = ((n1 * 8 + n2) * 8 + n3) * 8 + n4;
    const int kbase = (m1 * 8 + m2) * 16;
    float v[16];
    #pragma unroll
    for (int e = 0; e < 16; ++e) v[e] = 0.f;
    #pragma unroll
    for (int m3 = 0; m3 < 4; ++m3) {
        #pragma unroll
        for (int r3 = 0; r3 < 16; ++r3) {
            const float tv = t123[s][(m3 * 8 + n3) * 16 + r3];
            #pragma unroll
            for (int m4 = 0; m4 < 4; ++m4)
                v[m3 * 4 + m4] += tv * c3s[(r3 * 4 + m4) * 8 + n4];
        }
    }
    bf16x8 lo, hi;
    #pragma unroll
    for (int e = 0; e < 8; ++e) { lo[e] = (__bf16)v[e]; hi[e] = (__bf16)v[8 + e]; }
    *(bf16x8*)(wt + (size_t)n * 1024 + kbase)     = lo;
    *(bf16x8*)(wt + (size_t)n * 1024 + kbase + 8) = hi;
}

// -------------------------------------------------------------- GEMM + bias
// C[4096,4096] f32 = A[4096,1024] bf16 @ Bt[4096,1024]^T bf16 + bias
// Geometry: BM=BN=256, BK=64 (16 K-tiles), 8 waves 2Mx4N (wave 128x64),
// 512 threads, grid 256. LDS sA/sB[2 slots][2 ks][256x32] = 128 KB.
// MFMA 32x32x16: per ks-half per wave: A 4mi x 2kk, B 2ni x 2kk frags (12
// b128 reads), 16 MFMA. C/D: col=lane&31, row=(reg&3)+8*(reg>>2)+4*(lane>>5).
// Swizzle: 64-B rows, 4 x 16B chunks, phys chunk = logical ^ f(row),
//   f(r) = (r&2) | ((r>>2)&1)   [row-bit1 -> chunk-bit1: conflict-free]
// applied to BOTH the staging global source and the fragment read.

#define SCHED() __builtin_amdgcn_sched_barrier(0)
#define BAR()  do { SCHED(); __builtin_amdgcn_s_barrier(); SCHED(); } while (0)
#define WAITVM(n) do { SCHED(); asm volatile("s_waitcnt vmcnt(" #n ")"); SCHED(); } while (0)

__global__ __launch_bounds__(512, 2) void tt_gemm(
    const __bf16* __restrict__ A, const __bf16* __restrict__ B,
    const float* __restrict__ bias, float* __restrict__ C) {
    constexpr int K = 1024, N = 4096;
    constexpr int NKT = 16;                  // K-tiles of 64
    __shared__ __bf16 sA[2][2][256 * 32];    // [slot][ks][16 KB]
    __shared__ __bf16 sB[2][2][256 * 32];
    const int t = threadIdx.x;
    const int lane = t & 63;
    const int wave = t >> 6;                 // 0..7
    const int wm = (wave >> 2) * 128;        // 0 / 128   (M range of wave)
    const int wn = (wave & 3) * 64;          // 0..192    (N range of wave)
    const int l31 = lane & 31, lk = lane >> 5;
    // swizzled byte offset of (kk) sub-chunk for this lane's row (l31)
    const int key = (l31 & 2) | ((l31 >> 2) & 1);   // f(row)
    const int cO0 = ((0 * 2 + lk) ^ key) << 4;      // kk=0
    const int cO1 = ((1 * 2 + lk) ^ key) << 4;      // kk=1

    // XCD-aware mapping: each XCD owns an 8m x 4n rectangle of 256-tiles
    const int xcd = blockIdx.x & 7;
    const int lid = blockIdx.x >> 3;         // 0..31
    const int bm = ((xcd >> 2) * 8 + (lid & 7)) * 256;
    const int bn = ((xcd & 3) * 4 + (lid >> 3)) * 256;

    // staging: 16-KB ks-half = 1024 chunks of 16B; thread owns c = t, t+512
    const int c0i = t, c1i = t + 512;
    const int r0 = c0i >> 2, r1 = c1i >> 2;              // row in tile 0..255
    const int lc0 = (c0i & 3) ^ ((r0 & 2) | ((r0 >> 2) & 1));  // logical chunk
    const int lc1 = (c1i & 3) ^ ((r1 & 2) | ((r1 >> 2) & 1));
    const __bf16* a0p = A + (size_t)(bm + r0) * K + lc0 * 8;
    const __bf16* a1p = A + (size_t)(bm + r1) * K + lc1 * 8;
    const __bf16* b0p = B + (size_t)(bn + r0) * K + lc0 * 8;
    const __bf16* b1p = B + (size_t)(bn + r1) * K + lc1 * 8;

#define ST_A(kt, ks) do { \
    g2lds16(a0p + (size_t)(kt) * 64 + (ks) * 32, (char*)&sA[(kt) & 1][ks][0] + c0i * 16); \
    g2lds16(a1p + (size_t)(kt) * 64 + (ks) * 32, (char*)&sA[(kt) & 1][ks][0] + c1i * 16); } while (0)
#define ST_B(kt, ks) do { \
    g2lds16(b0p + (size_t)(kt) * 64 + (ks) * 32, (char*)&sB[(kt) & 1][ks][0] + c0i * 16); \
    g2lds16(b1p + (size_t)(kt) * 64 + (ks) * 32, (char*)&sB[(kt) & 1][ks][0] + c1i * 16); } while (0)
// 32x32 fragment loads (kk selects K-sub-16 inside the 32-k half)
#define LDA32(dst, mi, kk, ks) dst = *(const bf16x8*)((const char*)&sA[slot][ks][0] \
    + (wm + (mi) * 32 + l31) * 64 + ((kk) ? cO1 : cO0))
#define LDB32(dst, ni, kk, ks) dst = *(const bf16x8*)((const char*)&sB[slot][ks][0] \
    + (wn + (ni) * 32 + l31) * 64 + ((kk) ? cO1 : cO0))
// 16 MFMA 32x32x16 for one ks-half: a[4][2], b[2][2]
#define MFMA_HALF(a, b) do { \
    __builtin_amdgcn_s_setprio(1); \
    _Pragma("unroll") \
    for (int kk = 0; kk < 2; ++kk) \
        _Pragma("unroll") \
        for (int mi = 0; mi < 4; ++mi) \
            _Pragma("unroll") \
            for (int ni = 0; ni < 2; ++ni) \
                acc[mi][ni] = __builtin_amdgcn_mfma_f32_32x32x16_bf16( \
                    a[mi][kk], b[ni][kk], acc[mi][ni], 0, 0, 0); \
    __builtin_amdgcn_s_setprio(0); } while (0)

    f32x16 acc[4][2] = {};

    // prologue: 12 loads; WAITVM(4) -> oldest 8 done = tile0 BOTH halves present
    ST_A(0, 0); ST_B(0, 0);
    ST_A(0, 1); ST_B(0, 1);
    ST_A(1, 0); ST_B(1, 0);
    WAITVM(4);
    BAR();

    #pragma unroll 1
    for (int kt = 0; kt < NKT; ++kt) {
        const int slot = kt & 1;
        bf16x8 a0f[4][2], b0f[2][2], a1f[4][2], b1f[2][2];
        // ---- ks0 reads (12)
        #pragma unroll
        for (int mi = 0; mi < 4; ++mi) { LDA32(a0f[mi][0], mi, 0, 0); LDA32(a0f[mi][1], mi, 1, 0); }
        #pragma unroll
        for (int ni = 0; ni < 2; ++ni) { LDB32(b0f[ni][0], ni, 0, 0); LDB32(b0f[ni][1], ni, 1, 0); }
        // ---- hoisted ks1 reads (8 of 12): hide under ks0 MFMA
        #pragma unroll
        for (int ni = 0; ni < 2; ++ni) { LDB32(b1f[ni][0], ni, 0, 1); LDB32(b1f[ni][1], ni, 1, 1); }
        #pragma unroll
        for (int mi = 0; mi < 4; ++mi) LDA32(a1f[mi][0], mi, 0, 1);
        if (kt < NKT - 1) { ST_A(kt + 1, 1); ST_B(kt + 1, 1); }   // E1/E2
        MFMA_HALF(a0f, b0f);
        BAR();   // ks0 reads retired (lgkm waits on ks0 MFMAs) -> ks0 staging safe
        // ---- remaining ks1 reads (4) + E3/E4 stage + ks1 MFMA
        #pragma unroll
        for (int mi = 0; mi < 4; ++mi) LDA32(a1f[mi][1], mi, 1, 1);
        if (kt < NKT - 2) { ST_A(kt + 2, 0); ST_B(kt + 2, 0); }   // E3/E4
        MFMA_HALF(a1f, b1f);
        if (kt < NKT - 2)       { WAITVM(4); }   // certifies kt+1 both halves
        else if (kt == NKT - 2) { WAITVM(0); }   // drain for final tile
        BAR();
    }

    // epilogue: 32x32 C/D layout col=lane&31, row=(reg&3)+8*(reg>>2)+4*(lane>>5)
    // (m74/m101-verified); 32-lane contiguous 128B stores (WRITE_SIZE = ideal)
    float bv[2];
    #pragma unroll
    for (int ni = 0; ni < 2; ++ni) bv[ni] = bias[bn + wn + ni * 32 + l31];
    #pragma unroll
    for (int mi = 0; mi < 4; ++mi) {
        #pragma unroll
        for (int r = 0; r < 16; ++r) {
            const int row = bm + wm + mi * 32 + (r & 3) + 8 * (r >> 2) + 4 * lk;
            float* crow = C + (size_t)row * N + bn + wn + l31;
            crow[0]  = acc[mi][0][r] + bv[0];
            crow[32] = acc[mi][1][r] + bv[1];
        }
    }
#undef ST_A
#undef ST_B
#undef LDA32
#undef LDB32
#undef MFMA_HALF
}

extern "C" void kernel_launch(void* const* d_in, const int* in_sizes, int n_in,
                              void* d_out, int out_size, void* d_ws, size_t ws_size,
                              hipStream_t stream) {
    const float* x    = (const float*)d_in[0];
    const float* c0   = (const float*)d_in[1];
    const float* c1   = (const float*)d_in[2];
    const float* c2   = (const float*)d_in[3];
    const float* c3   = (const float*)d_in[4];
    const float* bias = (const float*)d_in[5];
    float* out = (float*)d_out;

    __bf16* xb = (__bf16*)d_ws;                    // 4096*1024 bf16 = 8.39 MB
    __bf16* wt = xb + (size_t)4096 * 1024;         // 4096*1024 bf16 = 8.39 MB

    prep<<<3072, 256, 0, stream>>>(x, xb, c0, c1, c2, c3, wt);
    tt_gemm<<<256, 512, 0, stream>>>(xb, wt, bias, out);
}

// Round 10
// 136.758 us; speedup vs baseline: 1.0196x; 1.0196x over previous
//
#include <hip/hip_runtime.h>
#include <hip/hip_bf16.h>
#include <cstdint>

// TT-linear: y[4096,4096] = x[4096,1024] @ W[1024,4096] + bias
// Kernel 1 (prep): fused x->bf16 convert + W^T reconstruction from TT cores (unchanged).
// Kernel 2 (tt_gemm): Round-10 = 2-blocks/CU with BALANCED wave tile.
//   R6's co-residency null used wave 128x32 (read:MFMA 1.54, LDS-heavy). This
//   round: block 256x128, 8 waves of 64x64 (acc=64 regs -> fits 128-reg cap for
//   4 waves/SIMD), BK=32, 3-slot LDS ring 72 KB -> 2 blocks/CU (144 KB).
//   read:MFMA = 8x12 : 16x4.85 = 1.23 (near-balanced). Mechanism: second block
//   fills first block's barrier-wait + exposed epilogue C-drain (~11 us).
//   16x16 MFMA only (R8/R9: 32x32 read shape conflicts under HW batch pairing
//   regardless of XOR function; 16x16 pattern measured 0 conflicts, R5/R7).
//   Ring: during kt stage kt+2 (3 loads/thread); WAITVM(3) at tile end gates
//   kt+1 (never drains mid-loop); 1 barrier/tile.

typedef __bf16 bf16x8 __attribute__((ext_vector_type(8)));
typedef float f32x4 __attribute__((ext_vector_type(4)));

__device__ __forceinline__ void g2lds16(const void* g, void* l) {
    __builtin_amdgcn_global_load_lds(
        (const __attribute__((address_space(1))) void*)g,
        (__attribute__((address_space(3))) void*)l,
        16, 0, 0);
}

// --------------------------------------------------------------------- prep
__global__ __launch_bounds__(256) void prep(
    const float* __restrict__ x, __bf16* __restrict__ xb,
    const float* __restrict__ c0, const float* __restrict__ c1,
    const float* __restrict__ c2, const float* __restrict__ c3,
    __bf16* __restrict__ wt) {
    const int b = blockIdx.x;
    const int t = threadIdx.x;
    if (b < 2048) {
        const int i = (b * 256 + t) * 8;
        float4 a0 = *(const float4*)(x + i);
        float4 a1 = *(const float4*)(x + i + 4);
        bf16x8 o;
        o[0] = (__bf16)a0.x; o[1] = (__bf16)a0.y; o[2] = (__bf16)a0.z; o[3] = (__bf16)a0.w;
        o[4] = (__bf16)a1.x; o[5] = (__bf16)a1.y; o[6] = (__bf16)a1.z; o[7] = (__bf16)a1.w;
        *(bf16x8*)(xb + i) = o;
        return;
    }
    __shared__ float t12[4][16];     // [wave][r2]
    __shared__ float t123[4][512];   // [wave][m3*8+n3][r3]
    __shared__ float c3s[512];       // [(r3*4+m4)*8+n4]
    #pragma unroll
    for (int i = t; i < 512; i += 256) c3s[i] = c3[i];
    const int s = t >> 6;
    const int lane = t & 63;
    const int g = (b - 2048) * 4 + s;
    const int m1 = g >> 9, n1 = (g >> 6) & 7, m2 = (g >> 3) & 7, n2 = g & 7;
    __syncthreads();
    if (lane < 16) {
        const int r2 = lane;
        float sum = 0.f;
        #pragma unroll
        for (int r1 = 0; r1 < 16; ++r1)
            sum += c0[(m1 * 8 + n1) * 16 + r1] * c1[((r1 * 8 + m2) * 8 + n2) * 16 + r2];
        t12[s][r2] = sum;
    }
    __syncthreads();
    #pragma unroll
    for (int idx = lane; idx < 512; idx += 64) {
        const int m3 = idx >> 7, n3 = (idx >> 4) & 7, r3 = idx & 15;
        float sum = 0.f;
        #pragma unroll
        for (int r2 = 0; r2 < 16; ++r2)
            sum += t12[s][r2] * c2[((r2 * 4 + m3) * 8 + n3) * 16 + r3];
        t123[s][(m3 * 8 + n3) * 16 + r3] = sum;
    }
    __syncthreads();
    const int n3 = lane >> 3, n4 = lane & 7;
    const int n = ((n1 * 8 + n2) * 8 + n3) * 8 + n4;
    const int kbase = (m1 * 8 + m2) * 16;
    float v[16];
    #pragma unroll
    for (int e = 0; e < 16; ++e) v[e] = 0.f;
    #pragma unroll
    for (int m3 = 0; m3 < 4; ++m3) {
        #pragma unroll
        for (int r3 = 0; r3 < 16; ++r3) {
            const float tv = t123[s][(m3 * 8 + n3) * 16 + r3];
            #pragma unroll
            for (int m4 = 0; m4 < 4; ++m4)
                v[m3 * 4 + m4] += tv * c3s[(r3 * 4 + m4) * 8 + n4];
        }
    }
    bf16x8 lo, hi;
    #pragma unroll
    for (int e = 0; e < 8; ++e) { lo[e] = (__bf16)v[e]; hi[e] = (__bf16)v[8 + e]; }
    *(bf16x8*)(wt + (size_t)n * 1024 + kbase)     = lo;
    *(bf16x8*)(wt + (size_t)n * 1024 + kbase + 8) = hi;
}

// -------------------------------------------------------------- GEMM + bias
// C[4096,4096] f32 = A[4096,1024] bf16 @ Bt[4096,1024]^T bf16 + bias
// Geometry: BM=256, BN=128, BK=32 (32 K-tiles), 8 waves 4Mx2N (wave 64x64),
// 512 threads, grid 512 (16 bm x 32 bn), 2 blocks/CU (LDS 72 KB, <=128 regs).
// LDS ring: sA[3][256x32] + sB[3][128x32] = 72 KB; tile kt in slot kt%3,
// staged during kt-2. WAITVM(3) at end of kt: 6 outstanding (kt+1:3, kt+2:3),
// waits oldest 3 => kt+1 fully in LDS. Slot safety: ST(kt+2) targets slot
// (kt+2)%3 = slot(kt-1), whose readers finished before the end-of-(kt-1)
// barrier. Swizzle: 64-B rows, 4 x 16B chunks, phys = logical ^ ((row>>1)&3)
// on both staging-source and read sides (R5/R7-verified: 0 conflicts).

#define SCHED() __builtin_amdgcn_sched_barrier(0)
#define BAR()  do { SCHED(); __builtin_amdgcn_s_barrier(); SCHED(); } while (0)
#define WAITVM(n) do { SCHED(); asm volatile("s_waitcnt vmcnt(" #n ")"); SCHED(); } while (0)

__global__ __launch_bounds__(512, 4) void tt_gemm(
    const __bf16* __restrict__ A, const __bf16* __restrict__ B,
    const float* __restrict__ bias, float* __restrict__ C) {
    constexpr int K = 1024, N = 4096;
    constexpr int NKT = 32;                  // K-tiles of 32
    __shared__ __bf16 sA[3][256 * 32];       // 3 x 16 KB
    __shared__ __bf16 sB[3][128 * 32];       // 3 x 8 KB
    const int t = threadIdx.x;
    const int lane = t & 63;
    const int wave = t >> 6;                 // 0..7
    const int wm = (wave >> 1) * 64;         // 0..192  (M range of wave)
    const int wn = (wave & 1) * 64;          // 0 / 64  (N range of wave)
    const int l15 = lane & 15, lh = lane >> 4;
    const int cOff = ((lh ^ ((l15 >> 1) & 3)) << 4);  // swizzled 16B chunk in 64-B row

    // XCD-aware mapping: each XCD owns an 8bm x 8bn patch (bijective, 512 blocks)
    const int xcd = blockIdx.x & 7;
    const int lid = blockIdx.x >> 3;         // 0..63
    const int bm = ((xcd >> 2) * 8 + (lid & 7)) * 256;   // 16 bm values
    const int bn = ((xcd & 3) * 8 + (lid >> 3)) * 128;   // 32 bn values

    // staging: A tile = 1024 chunks of 16B (thread owns t, t+512);
    //          B tile = 512 chunks (thread owns t)
    const int c0i = t, c1i = t + 512;
    const int rA0 = c0i >> 2, rA1 = c1i >> 2;            // A row 0..255
    const int lcA0 = (c0i & 3) ^ ((rA0 >> 1) & 3);       // logical chunk (global)
    const int lcA1 = (c1i & 3) ^ ((rA1 >> 1) & 3);
    const int rB = t >> 2;                               // B row 0..127
    const int lcB = (t & 3) ^ ((rB >> 1) & 3);
    const __bf16* a0p = A + (size_t)(bm + rA0) * K + lcA0 * 8;
    const __bf16* a1p = A + (size_t)(bm + rA1) * K + lcA1 * 8;
    const __bf16* bp  = B + (size_t)(bn + rB)  * K + lcB * 8;

#define ST(kt, sl) do { \
    g2lds16(a0p + (size_t)(kt) * 32, (char*)&sA[sl][0] + c0i * 16); \
    g2lds16(a1p + (size_t)(kt) * 32, (char*)&sA[sl][0] + c1i * 16); \
    g2lds16(bp  + (size_t)(kt) * 32, (char*)&sB[sl][0] + t * 16); } while (0)
#define LDA(dst, mi) dst = *(const bf16x8*)((const char*)&sA[s0][0] + (wm + (mi) * 16 + l15) * 64 + cOff)
#define LDB(dst, ni) dst = *(const bf16x8*)((const char*)&sB[s0][0] + (wn + (ni) * 16 + l15) * 64 + cOff)

    f32x4 acc[4][4] = {};

    // prologue: stage tiles 0 (slot0) and 1 (slot1) = 6 loads; oldest 3 = tile 0
    ST(0, 0);
    ST(1, 1);
    WAITVM(3);
    BAR();

    #pragma unroll 1
    for (int kt = 0; kt < NKT; ++kt) {
        const int s0 = kt % 3;
        const int s2 = (kt + 2) % 3;
        bf16x8 af[4], bf[4];
        // all 8 frag reads hoisted; stage kt+2; 16 MFMA; counted wait; barrier
        #pragma unroll
        for (int mi = 0; mi < 4; ++mi) LDA(af[mi], mi);
        #pragma unroll
        for (int ni = 0; ni < 4; ++ni) LDB(bf[ni], ni);
        if (kt < NKT - 2) ST(kt + 2, s2);
        __builtin_amdgcn_s_setprio(1);
        #pragma unroll
        for (int mi = 0; mi < 4; ++mi)
            #pragma unroll
            for (int ni = 0; ni < 4; ++ni)
                acc[mi][ni] = __builtin_amdgcn_mfma_f32_16x16x32_bf16(
                    af[mi], bf[ni], acc[mi][ni], 0, 0, 0);
        __builtin_amdgcn_s_setprio(0);
        if (kt < NKT - 2)       { WAITVM(3); }   // gates kt+1; never drains
        else if (kt == NKT - 2) { WAITVM(0); }   // drain for final tile
        BAR();
    }

    // epilogue: C/D layout col=lane&15, row=(lane>>4)*4+reg (m89-verified);
    // ni-inner store order -> 256B contiguous per wave-row
    float bv[4];
    #pragma unroll
    for (int ni = 0; ni < 4; ++ni) bv[ni] = bias[bn + wn + ni * 16 + l15];
    #pragma unroll
    for (int mi = 0; mi < 4; ++mi) {
        #pragma unroll
        for (int r = 0; r < 4; ++r) {
            const int row = bm + wm + mi * 16 + lh * 4 + r;
            float* crow = C + (size_t)row * N + bn + wn + l15;
            #pragma unroll
            for (int ni = 0; ni < 4; ++ni)
                crow[ni * 16] = acc[mi][ni][r] + bv[ni];
        }
    }
#undef ST
#undef LDA
#undef LDB
}

extern "C" void kernel_launch(void* const* d_in, const int* in_sizes, int n_in,
                              void* d_out, int out_size, void* d_ws, size_t ws_size,
                              hipStream_t stream) {
    const float* x    = (const float*)d_in[0];
    const float* c0   = (const float*)d_in[1];
    const float* c1   = (const float*)d_in[2];
    const float* c2   = (const float*)d_in[3];
    const float* c3   = (const float*)d_in[4];
    const float* bias = (const float*)d_in[5];
    float* out = (float*)d_out;

    __bf16* xb = (__bf16*)d_ws;                    // 4096*1024 bf16 = 8.39 MB
    __bf16* wt = xb + (size_t)4096 * 1024;         // 4096*1024 bf16 = 8.39 MB

    prep<<<3072, 256, 0, stream>>>(x, xb, c0, c1, c2, c3, wt);
    tt_gemm<<<512, 512, 0, stream>>>(xb, wt, bias, out);
}

// Round 11
// 135.832 us; speedup vs baseline: 1.0266x; 1.0068x over previous
//
#include <hip/hip_runtime.h>
#include <hip/hip_bf16.h>
#include <cstdint>

// TT-linear: y[4096,4096] = x[4096,1024] @ W[1024,4096] + bias
// Kernel 1 (prep): fused x->bf16 convert + W^T reconstruction from TT cores (unchanged).
// Kernel 2 (tt_gemm): Round-11 = R10 co-residency + R7's balanced wave shape.
//   Block 256x128, 4 waves of 128x64 (2Mx2N), 256 threads, BK=32, 3-slot ring
//   (72 KB -> 2 blocks/CU), launch_bounds(256,2) (<=256 VGPR, 2 waves/SIMD,
//   4 blocks... 2 blocks/CU by LDS).
//   R6/R10 A/B isolated the rule: co-residency pays iff wave read:MFMA ~< 1.
//   R10 (64x64, ratio 1.23, amp 2.67x) -> gemm <45.6; this round (128x64,
//   ratio 0.93, amp 2.0x, 48KB reads/tile vs 64KB) pushes the same lever.
//   Carried unchanged: 16x16x32 MFMA (32x32 conflicts under HW batch pairing,
//   R8/R9), swizzle phys=logical^((row>>1)&3) both sides (0 conflicts,
//   R5/R7/R10), stage-2-ahead ring with counted vmcnt (6 loads/thread/tile
//   -> WAITVM(6) gates kt+1; never drains mid-loop), 1 barrier/tile,
//   XCD-bijective block map, ni-inner epilogue.

typedef __bf16 bf16x8 __attribute__((ext_vector_type(8)));
typedef float f32x4 __attribute__((ext_vector_type(4)));

__device__ __forceinline__ void g2lds16(const void* g, void* l) {
    __builtin_amdgcn_global_load_lds(
        (const __attribute__((address_space(1))) void*)g,
        (__attribute__((address_space(3))) void*)l,
        16, 0, 0);
}

// --------------------------------------------------------------------- prep
__global__ __launch_bounds__(256) void prep(
    const float* __restrict__ x, __bf16* __restrict__ xb,
    const float* __restrict__ c0, const float* __restrict__ c1,
    const float* __restrict__ c2, const float* __restrict__ c3,
    __bf16* __restrict__ wt) {
    const int b = blockIdx.x;
    const int t = threadIdx.x;
    if (b < 2048) {
        const int i = (b * 256 + t) * 8;
        float4 a0 = *(const float4*)(x + i);
        float4 a1 = *(const float4*)(x + i + 4);
        bf16x8 o;
        o[0] = (__bf16)a0.x; o[1] = (__bf16)a0.y; o[2] = (__bf16)a0.z; o[3] = (__bf16)a0.w;
        o[4] = (__bf16)a1.x; o[5] = (__bf16)a1.y; o[6] = (__bf16)a1.z; o[7] = (__bf16)a1.w;
        *(bf16x8*)(xb + i) = o;
        return;
    }
    __shared__ float t12[4][16];     // [wave][r2]
    __shared__ float t123[4][512];   // [wave][m3*8+n3][r3]
    __shared__ float c3s[512];       // [(r3*4+m4)*8+n4]
    #pragma unroll
    for (int i = t; i < 512; i += 256) c3s[i] = c3[i];
    const int s = t >> 6;
    const int lane = t & 63;
    const int g = (b - 2048) * 4 + s;
    const int m1 = g >> 9, n1 = (g >> 6) & 7, m2 = (g >> 3) & 7, n2 = g & 7;
    __syncthreads();
    if (lane < 16) {
        const int r2 = lane;
        float sum = 0.f;
        #pragma unroll
        for (int r1 = 0; r1 < 16; ++r1)
            sum += c0[(m1 * 8 + n1) * 16 + r1] * c1[((r1 * 8 + m2) * 8 + n2) * 16 + r2];
        t12[s][r2] = sum;
    }
    __syncthreads();
    #pragma unroll
    for (int idx = lane; idx < 512; idx += 64) {
        const int m3 = idx >> 7, n3 = (idx >> 4) & 7, r3 = idx & 15;
        float sum = 0.f;
        #pragma unroll
        for (int r2 = 0; r2 < 16; ++r2)
            sum += t12[s][r2] * c2[((r2 * 4 + m3) * 8 + n3) * 16 + r3];
        t123[s][(m3 * 8 + n3) * 16 + r3] = sum;
    }
    __syncthreads();
    const int n3 = lane >> 3, n4 = lane & 7;
    const int n = ((n1 * 8 + n2) * 8 + n3) * 8 + n4;
    const int kbase = (m1 * 8 + m2) * 16;
    float v[16];
    #pragma unroll
    for (int e = 0; e < 16; ++e) v[e] = 0.f;
    #pragma unroll
    for (int m3 = 0; m3 < 4; ++m3) {
        #pragma unroll
        for (int r3 = 0; r3 < 16; ++r3) {
            const float tv = t123[s][(m3 * 8 + n3) * 16 + r3];
            #pragma unroll
            for (int m4 = 0; m4 < 4; ++m4)
                v[m3 * 4 + m4] += tv * c3s[(r3 * 4 + m4) * 8 + n4];
        }
    }
    bf16x8 lo, hi;
    #pragma unroll
    for (int e = 0; e < 8; ++e) { lo[e] = (__bf16)v[e]; hi[e] = (__bf16)v[8 + e]; }
    *(bf16x8*)(wt + (size_t)n * 1024 + kbase)     = lo;
    *(bf16x8*)(wt + (size_t)n * 1024 + kbase + 8) = hi;
}

// -------------------------------------------------------------- GEMM + bias
// C[4096,4096] f32 = A[4096,1024] bf16 @ Bt[4096,1024]^T bf16 + bias
// Geometry: BM=256, BN=128, BK=32 (32 K-tiles), 4 waves 2Mx2N (wave 128x64),
// 256 threads, grid 512 (16 bm x 32 bn), 2 blocks/CU (LDS 72 KB).
// LDS ring: sA[3][256x32] + sB[3][128x32]; tile kt in slot kt%3, staged
// during kt-2 (6 g2lds16/thread). WAITVM(6) at end of kt: 12 outstanding
// (kt+1:6, kt+2:6), waits oldest 6 => kt+1 fully in LDS; never drains.
// Slot safety: ST(kt+2) targets slot(kt-1); its readers retired before the
// end-of-(kt-1) barrier (ds_read data consumed by MFMA before BAR).
// Swizzle: 64-B rows, 4 x 16B chunks, phys = logical ^ ((row>>1)&3) on both
// staging-source and read sides (R5/R7/R10-verified: 0 conflicts).

#define SCHED() __builtin_amdgcn_sched_barrier(0)
#define BAR()  do { SCHED(); __builtin_amdgcn_s_barrier(); SCHED(); } while (0)
#define WAITVM(n) do { SCHED(); asm volatile("s_waitcnt vmcnt(" #n ")"); SCHED(); } while (0)

__global__ __launch_bounds__(256, 2) void tt_gemm(
    const __bf16* __restrict__ A, const __bf16* __restrict__ B,
    const float* __restrict__ bias, float* __restrict__ C) {
    constexpr int K = 1024, N = 4096;
    constexpr int NKT = 32;                  // K-tiles of 32
    __shared__ __bf16 sA[3][256 * 32];       // 3 x 16 KB
    __shared__ __bf16 sB[3][128 * 32];       // 3 x 8 KB
    const int t = threadIdx.x;
    const int lane = t & 63;
    const int wave = t >> 6;                 // 0..3
    const int wm = (wave >> 1) * 128;        // 0 / 128  (M range of wave)
    const int wn = (wave & 1) * 64;          // 0 / 64   (N range of wave)
    const int l15 = lane & 15, lh = lane >> 4;
    const int cOff = ((lh ^ ((l15 >> 1) & 3)) << 4);  // swizzled 16B chunk in 64-B row

    // XCD-aware mapping: each XCD owns an 8bm x 8bn patch (bijective, 512 blocks)
    const int xcd = blockIdx.x & 7;
    const int lid = blockIdx.x >> 3;         // 0..63
    const int bm = ((xcd >> 2) * 8 + (lid & 7)) * 256;   // 16 bm values
    const int bn = ((xcd & 3) * 8 + (lid >> 3)) * 128;   // 32 bn values

    // staging: A tile = 1024 x 16B chunks (thread owns t, t+256, t+512, t+768);
    //          B tile = 512 chunks (thread owns t, t+256)
    const __bf16* ap[4];
    const __bf16* bp[2];
    #pragma unroll
    for (int j = 0; j < 4; ++j) {
        const int c = t + j * 256;
        const int r = c >> 2;                            // A row 0..255
        const int lc = (c & 3) ^ ((r >> 1) & 3);         // logical chunk (global)
        ap[j] = A + (size_t)(bm + r) * K + lc * 8;
    }
    #pragma unroll
    for (int j = 0; j < 2; ++j) {
        const int c = t + j * 256;
        const int r = c >> 2;                            // B row 0..127
        const int lc = (c & 3) ^ ((r >> 1) & 3);
        bp[j] = B + (size_t)(bn + r) * K + lc * 8;
    }

#define ST(kt, sl) do { \
    _Pragma("unroll") \
    for (int j = 0; j < 4; ++j) \
        g2lds16(ap[j] + (size_t)(kt) * 32, (char*)&sA[sl][0] + (t + j * 256) * 16); \
    _Pragma("unroll") \
    for (int j = 0; j < 2; ++j) \
        g2lds16(bp[j] + (size_t)(kt) * 32, (char*)&sB[sl][0] + (t + j * 256) * 16); \
} while (0)
#define LDA(dst, mi) dst = *(const bf16x8*)((const char*)&sA[s0][0] + (wm + (mi) * 16 + l15) * 64 + cOff)
#define LDB(dst, ni) dst = *(const bf16x8*)((const char*)&sB[s0][0] + (wn + (ni) * 16 + l15) * 64 + cOff)

    f32x4 acc[8][4] = {};

    // prologue: stage tiles 0 (slot0) and 1 (slot1) = 12 loads; oldest 6 = tile 0
    ST(0, 0);
    ST(1, 1);
    WAITVM(6);
    BAR();

    #pragma unroll 1
    for (int kt = 0; kt < NKT; ++kt) {
        const int s0 = kt % 3;
        const int s2 = (kt + 2) % 3;
        bf16x8 af[8], bf[4];
        // 12 frag reads; stage kt+2; 32 MFMA; counted wait; barrier
        #pragma unroll
        for (int mi = 0; mi < 8; ++mi) LDA(af[mi], mi);
        #pragma unroll
        for (int ni = 0; ni < 4; ++ni) LDB(bf[ni], ni);
        if (kt < NKT - 2) ST(kt + 2, s2);
        __builtin_amdgcn_s_setprio(1);
        #pragma unroll
        for (int mi = 0; mi < 8; ++mi)
            #pragma unroll
            for (int ni = 0; ni < 4; ++ni)
                acc[mi][ni] = __builtin_amdgcn_mfma_f32_16x16x32_bf16(
                    af[mi], bf[ni], acc[mi][ni], 0, 0, 0);
        __builtin_amdgcn_s_setprio(0);
        if (kt < NKT - 2)       { WAITVM(6); }   // gates kt+1; never drains
        else if (kt == NKT - 2) { WAITVM(0); }   // drain for final tile
        BAR();
    }

    // epilogue: C/D layout col=lane&15, row=(lane>>4)*4+reg (m89-verified);
    // ni-inner store order -> 256B contiguous per wave-row
    float bv[4];
    #pragma unroll
    for (int ni = 0; ni < 4; ++ni) bv[ni] = bias[bn + wn + ni * 16 + l15];
    #pragma unroll
    for (int mi = 0; mi < 8; ++mi) {
        #pragma unroll
        for (int r = 0; r < 4; ++r) {
            const int row = bm + wm + mi * 16 + lh * 4 + r;
            float* crow = C + (size_t)row * N + bn + wn + l15;
            #pragma unroll
            for (int ni = 0; ni < 4; ++ni)
                crow[ni * 16] = acc[mi][ni][r] + bv[ni];
        }
    }
#undef ST
#undef LDA
#undef LDB
}

extern "C" void kernel_launch(void* const* d_in, const int* in_sizes, int n_in,
                              void* d_out, int out_size, void* d_ws, size_t ws_size,
                              hipStream_t stream) {
    const float* x    = (const float*)d_in[0];
    const float* c0   = (const float*)d_in[1];
    const float* c1   = (const float*)d_in[2];
    const float* c2   = (const float*)d_in[3];
    const float* c3   = (const float*)d_in[4];
    const float* bias = (const float*)d_in[5];
    float* out = (float*)d_out;

    __bf16* xb = (__bf16*)d_ws;                    // 4096*1024 bf16 = 8.39 MB
    __bf16* wt = xb + (size_t)4096 * 1024;         // 4096*1024 bf16 = 8.39 MB

    prep<<<3072, 256, 0, stream>>>(x, xb, c0, c1, c2, c3, wt);
    tt_gemm<<<512, 256, 0, stream>>>(xb, wt, bias, out);
}